// Round 9
// baseline (246.239 us; speedup 1.0000x reference)
//
#include <hip/hip_runtime.h>
#include <hip/hip_bf16.h>

// N=100000 nodes, D=64 feat, H=256 hidden, E=1000000 edges per relation.
#define N_NODES 100000
#define DIM 64
#define HID 256
#define E_EDGES 1000000
#define TWO_N (2 * N_NODES)
#define MLP_ROWBLOCKS (TWO_N / 64)                   // 3125 blocks of 64 z-rows

// Binned aggregation.
#define TILE 120                                     // nodes per bin
#define NBINS 834                                    // ceil(100000/120)
#define CAP 1600                                     // mean 1200, sd ~35
#define EPB 4096                                     // edges per bin_fill block
#define FILL_BLOCKS 245                              // ceil(E/EPB)
#define FEAT_BLOCKS ((N_NODES * DIM / 4) / 256)      // 6250

typedef short short8 __attribute__((ext_vector_type(8)));   // 8 bf16 (4 VGPRs)
typedef float f32x4 __attribute__((ext_vector_type(4)));
typedef unsigned short us4 __attribute__((ext_vector_type(4)));

__device__ __forceinline__ float tanh_fast(float x) {
    x = fminf(fmaxf(x, -15.0f), 15.0f);
    float e = __expf(2.0f * x);
    return (e - 1.0f) / (e + 1.0f);
}

__device__ __forceinline__ unsigned short f2bf(float x) {   // RNE f32->bf16
    unsigned u = __float_as_uint(x);
    u = u + 0x7FFFu + ((u >> 16) & 1u);
    return (unsigned short)(u >> 16);
}

__device__ __forceinline__ float bf2f(unsigned short u) {
    return __uint_as_float(((unsigned)u) << 16);
}

// ---------- pack: feat -> bf16 (blocks 0..FEAT_BLOCKS-1) + W1 -> B-frag bf16 (last) ----
__global__ void pack_kernel(const float* __restrict__ feat, unsigned short* __restrict__ fb,
                            const float* __restrict__ W1, unsigned short* __restrict__ W1p) {
    int b = blockIdx.x;
    if (b < FEAT_BLOCKS) {
        int i = b * 256 + threadIdx.x;               // one float4 -> ushort4
        float4 v = ((const float4*)feat)[i];
        us4 o;
        o[0] = f2bf(v.x); o[1] = f2bf(v.y); o[2] = f2bf(v.z); o[3] = f2bf(v.w);
        ((us4*)fb)[i] = o;
    } else {
        // W1p[(((n*2+khalf)*4+q)*16+nidx)*8+j] = bf16(W1[32*khalf+8*q+j][16*n+nidx])
        for (int i = threadIdx.x; i < 16384; i += 256) {
            int j = i & 7;
            int r = i >> 3;
            int nidx = r & 15; r >>= 4;
            int q = r & 3; r >>= 2;
            int khalf = r & 1;
            int n = r >> 1;
            int k = 32 * khalf + 8 * q + j;
            int c = 16 * n + nidx;
            W1p[i] = f2bf(W1[k * HID + c]);
        }
    }
}

// ---------- Phase A: block-local counting sort by bin + coalesced copy-out ----------
__global__ void __launch_bounds__(512) bin_fill_kernel(
        const int* __restrict__ gs, const int* __restrict__ gd,
        const int* __restrict__ ts, const int* __restrict__ td,
        const float* __restrict__ tw,
        int* __restrict__ gcount,
        int* __restrict__ gbin, int2* __restrict__ tbin) {
    __shared__ int   hist[NBINS];
    __shared__ int   adjS[NBINS];                    // gbase - lbase per bin
    __shared__ int   curS[NBINS];
    __shared__ int   pS[EPB];                        // sorted payload (src|dloc<<20)
    __shared__ float w2S[EPB];                       // sorted weights (trans only)
    __shared__ unsigned short binS[EPB];             // bin of sorted slot
    __shared__ int   wsumS[8];

    int t = threadIdx.x, lane = t & 63, wid = t >> 6;
    int blk = blockIdx.x;
    int rel = (blk >= FILL_BLOCKS) ? 1 : 0;
    int e0 = (rel ? blk - FILL_BLOCKS : blk) * EPB;
    const int* dstp = rel ? td : gd;
    const int* srcp = rel ? ts : gs;

    for (int i = t; i < NBINS; i += 512) hist[i] = 0;
    __syncthreads();

    // Load 8 edges per thread into registers (int4 reads), histogram.
    int d_[8], s_[8];
    float w_[8];
    #pragma unroll
    for (int j = 0; j < 2; ++j) {
        int idx = e0 + j * 2048 + 4 * t;
        if (idx + 3 < E_EDGES) {
            int4 dv = *(const int4*)&dstp[idx];
            int4 sv = *(const int4*)&srcp[idx];
            d_[4*j+0] = dv.x; d_[4*j+1] = dv.y; d_[4*j+2] = dv.z; d_[4*j+3] = dv.w;
            s_[4*j+0] = sv.x; s_[4*j+1] = sv.y; s_[4*j+2] = sv.z; s_[4*j+3] = sv.w;
            if (rel) {
                float4 wv = *(const float4*)&tw[idx];
                w_[4*j+0] = wv.x; w_[4*j+1] = wv.y; w_[4*j+2] = wv.z; w_[4*j+3] = wv.w;
            }
        } else {
            #pragma unroll
            for (int i2 = 0; i2 < 4; ++i2) {
                bool ok = (idx + i2 < E_EDGES);
                d_[4*j+i2] = ok ? dstp[idx + i2] : -1;
                s_[4*j+i2] = ok ? srcp[idx + i2] : 0;
                w_[4*j+i2] = (ok && rel) ? tw[idx + i2] : 0.0f;
            }
        }
    }
    #pragma unroll
    for (int i = 0; i < 8; ++i)
        if (d_[i] >= 0) atomicAdd(&hist[d_[i] / TILE], 1);
    __syncthreads();

    // Exclusive scan over NBINS via shfl (thread owns bins 2t, 2t+1) — 2 barriers.
    int b0i = 2 * t, b1i = 2 * t + 1;
    int h0 = (b0i < NBINS) ? hist[b0i] : 0;
    int h1 = (b1i < NBINS) ? hist[b1i] : 0;
    int c = h0 + h1;
    int v = c;
    #pragma unroll
    for (int off = 1; off < 64; off <<= 1) {
        int u = __shfl_up(v, off);
        if (lane >= off) v += u;
    }
    if (lane == 63) wsumS[wid] = v;
    __syncthreads();
    if (t == 0) {
        int run = 0;
        #pragma unroll
        for (int i = 0; i < 8; ++i) { int x = wsumS[i]; wsumS[i] = run; run += x; }
    }
    __syncthreads();
    int excl = v - c + wsumS[wid];
    if (b0i < NBINS) {
        curS[b0i] = excl;
        int gb = (h0 > 0) ? (b0i * CAP + atomicAdd(&gcount[rel * NBINS + b0i], h0)) : 0;
        adjS[b0i] = gb - excl;
    }
    if (b1i < NBINS) {
        int lb1 = excl + h0;
        curS[b1i] = lb1;
        int gb = (h1 > 0) ? (b1i * CAP + atomicAdd(&gcount[rel * NBINS + b1i], h1)) : 0;
        adjS[b1i] = gb - lb1;
    }
    __syncthreads();

    // Place into sorted LDS order.
    #pragma unroll
    for (int i = 0; i < 8; ++i) {
        int d = d_[i];
        if (d < 0) continue;
        int bin = d / TILE;
        int pos = atomicAdd(&curS[bin], 1);
        pS[pos] = s_[i] | ((d - bin * TILE) << 20);
        binS[pos] = (unsigned short)bin;
        if (rel) w2S[pos] = w_[i];
    }
    __syncthreads();

    // Coalesced copy-out: consecutive slots in a bin -> consecutive global addrs.
    int nV = min(EPB, E_EDGES - e0);
    if (!rel) {
        for (int i = t; i < nV; i += 512) {
            int b = binS[i];
            int gi = adjS[b] + i;
            if (gi < (b + 1) * CAP)                          // overflow guard (P~0)
                gbin[gi] = pS[i];
        }
    } else {
        for (int i = t; i < nV; i += 512) {
            int b = binS[i];
            int gi = adjS[b] + i;
            if (gi < (b + 1) * CAP)
                tbin[gi] = make_int2(pS[i], __float_as_int(w2S[i]));
        }
    }
}

// ---------- Phase B: LDS counting sort + quarter-wave-per-node gather (unroll-8) ------
// zb rows 0..N-1 = geo MEAN; rows N..2N-1 = trans weighted sum. bf16 output.
__global__ void __launch_bounds__(256) aggregate_kernel(
        const unsigned short* __restrict__ featb,
        const int* __restrict__ gbin, const int2* __restrict__ tbin,
        const int* __restrict__ gcount,
        unsigned short* __restrict__ zb) {
    __shared__ int   srcS[CAP];      // 6.4 KB sorted src ids
    __shared__ float wS[CAP];        // 6.4 KB sorted weights (trans only)
    __shared__ int   histS[TILE];
    __shared__ int   baseS[TILE];
    __shared__ int   curS[TILE];
    __shared__ int   w0sum[1];

    int b = blockIdx.x;
    int rel = (b >= NBINS) ? 1 : 0;
    int bin = rel ? b - NBINS : b;
    int node0 = bin * TILE;
    int nNodes = min(TILE, N_NODES - node0);
    int t = threadIdx.x, lane = t & 63, wave = t >> 6;   // 4 waves
    int q = lane >> 4, ql = lane & 15;                   // quarter / lane-in-quarter

    int nE = gcount[b];
    if (nE > CAP) nE = CAP;

    for (int i = t; i < TILE; i += 256) histS[i] = 0;
    __syncthreads();

    // Pass 1: histogram over local dst.
    if (!rel) {
        const int* bp = gbin + (size_t)bin * CAP;
        for (int i = t; i < nE; i += 256) atomicAdd(&histS[bp[i] >> 20], 1);
    } else {
        const int2* bp = tbin + (size_t)bin * CAP;
        for (int i = t; i < nE; i += 256) atomicAdd(&histS[bp[i].x >> 20], 1);
    }
    __syncthreads();

    // Exclusive scan over TILE=120 via shfl (waves 0,1) — 2 barriers.
    int h = (t < TILE) ? histS[t] : 0;
    int v = h;
    #pragma unroll
    for (int off = 1; off < 64; off <<= 1) {
        int u = __shfl_up(v, off);
        if (lane >= off) v += u;
    }
    if (t == 63) w0sum[0] = v;
    __syncthreads();
    if (wave == 1) v += w0sum[0];
    if (t < TILE) {
        int base = v - h;
        baseS[t] = base;
        curS[t] = base;
    }
    __syncthreads();

    // Pass 2: place payload into sorted LDS lists.
    if (!rel) {
        const int* bp = gbin + (size_t)bin * CAP;
        for (int i = t; i < nE; i += 256) {
            int p = bp[i];
            int pos = atomicAdd(&curS[p >> 20], 1);
            srcS[pos] = p & 0xFFFFF;
        }
    } else {
        const int2* bp = tbin + (size_t)bin * CAP;
        for (int i = t; i < nE; i += 256) {
            int2 p = bp[i];
            int pos = atomicAdd(&curS[p.x >> 20], 1);
            srcS[pos] = p.x & 0xFFFFF;
            wS[pos] = __int_as_float(p.y);
        }
    }
    __syncthreads();

    // Pass 3: quarter q owns node nl0+q (full 128B row via 16 lanes x 8B).
    // unroll-8 -> 8 independent row loads in flight per quarter.
    for (int nl0 = wave * 4; nl0 < nNodes; nl0 += 16) {
        int nl = nl0 + q;
        bool act = (nl < nNodes);
        int deg = act ? histS[nl] : 0;
        int base = act ? baseS[nl] : 0;
        float a0 = 0.f, a1 = 0.f, a2 = 0.f, a3 = 0.f;
        if (!rel) {
            int k = 0;
            for (; k + 7 < deg; k += 8) {
                int s0 = srcS[base + k],     s1 = srcS[base + k + 1];
                int s2 = srcS[base + k + 2], s3 = srcS[base + k + 3];
                int s4 = srcS[base + k + 4], s5 = srcS[base + k + 5];
                int s6 = srcS[base + k + 6], s7 = srcS[base + k + 7];
                us4 r0 = *(const us4*)&featb[(size_t)s0 * DIM + ql * 4];
                us4 r1 = *(const us4*)&featb[(size_t)s1 * DIM + ql * 4];
                us4 r2 = *(const us4*)&featb[(size_t)s2 * DIM + ql * 4];
                us4 r3 = *(const us4*)&featb[(size_t)s3 * DIM + ql * 4];
                us4 r4 = *(const us4*)&featb[(size_t)s4 * DIM + ql * 4];
                us4 r5 = *(const us4*)&featb[(size_t)s5 * DIM + ql * 4];
                us4 r6 = *(const us4*)&featb[(size_t)s6 * DIM + ql * 4];
                us4 r7 = *(const us4*)&featb[(size_t)s7 * DIM + ql * 4];
                a0 += ((bf2f(r0[0]) + bf2f(r1[0])) + (bf2f(r2[0]) + bf2f(r3[0])))
                    + ((bf2f(r4[0]) + bf2f(r5[0])) + (bf2f(r6[0]) + bf2f(r7[0])));
                a1 += ((bf2f(r0[1]) + bf2f(r1[1])) + (bf2f(r2[1]) + bf2f(r3[1])))
                    + ((bf2f(r4[1]) + bf2f(r5[1])) + (bf2f(r6[1]) + bf2f(r7[1])));
                a2 += ((bf2f(r0[2]) + bf2f(r1[2])) + (bf2f(r2[2]) + bf2f(r3[2])))
                    + ((bf2f(r4[2]) + bf2f(r5[2])) + (bf2f(r6[2]) + bf2f(r7[2])));
                a3 += ((bf2f(r0[3]) + bf2f(r1[3])) + (bf2f(r2[3]) + bf2f(r3[3])))
                    + ((bf2f(r4[3]) + bf2f(r5[3])) + (bf2f(r6[3]) + bf2f(r7[3])));
            }
            for (; k + 1 < deg; k += 2) {
                int s0 = srcS[base + k], s1 = srcS[base + k + 1];
                us4 r0 = *(const us4*)&featb[(size_t)s0 * DIM + ql * 4];
                us4 r1 = *(const us4*)&featb[(size_t)s1 * DIM + ql * 4];
                a0 += bf2f(r0[0]) + bf2f(r1[0]);
                a1 += bf2f(r0[1]) + bf2f(r1[1]);
                a2 += bf2f(r0[2]) + bf2f(r1[2]);
                a3 += bf2f(r0[3]) + bf2f(r1[3]);
            }
            if (k < deg) {
                int s = srcS[base + k];
                us4 r = *(const us4*)&featb[(size_t)s * DIM + ql * 4];
                a0 += bf2f(r[0]); a1 += bf2f(r[1]);
                a2 += bf2f(r[2]); a3 += bf2f(r[3]);
            }
        } else {
            int k = 0;
            for (; k + 7 < deg; k += 8) {
                int s0 = srcS[base + k],     s1 = srcS[base + k + 1];
                int s2 = srcS[base + k + 2], s3 = srcS[base + k + 3];
                int s4 = srcS[base + k + 4], s5 = srcS[base + k + 5];
                int s6 = srcS[base + k + 6], s7 = srcS[base + k + 7];
                float w0 = wS[base + k],     w1 = wS[base + k + 1];
                float w2 = wS[base + k + 2], w3 = wS[base + k + 3];
                float w4 = wS[base + k + 4], w5 = wS[base + k + 5];
                float w6 = wS[base + k + 6], w7 = wS[base + k + 7];
                us4 r0 = *(const us4*)&featb[(size_t)s0 * DIM + ql * 4];
                us4 r1 = *(const us4*)&featb[(size_t)s1 * DIM + ql * 4];
                us4 r2 = *(const us4*)&featb[(size_t)s2 * DIM + ql * 4];
                us4 r3 = *(const us4*)&featb[(size_t)s3 * DIM + ql * 4];
                us4 r4 = *(const us4*)&featb[(size_t)s4 * DIM + ql * 4];
                us4 r5 = *(const us4*)&featb[(size_t)s5 * DIM + ql * 4];
                us4 r6 = *(const us4*)&featb[(size_t)s6 * DIM + ql * 4];
                us4 r7 = *(const us4*)&featb[(size_t)s7 * DIM + ql * 4];
                a0 += ((bf2f(r0[0])*w0 + bf2f(r1[0])*w1) + (bf2f(r2[0])*w2 + bf2f(r3[0])*w3))
                    + ((bf2f(r4[0])*w4 + bf2f(r5[0])*w5) + (bf2f(r6[0])*w6 + bf2f(r7[0])*w7));
                a1 += ((bf2f(r0[1])*w0 + bf2f(r1[1])*w1) + (bf2f(r2[1])*w2 + bf2f(r3[1])*w3))
                    + ((bf2f(r4[1])*w4 + bf2f(r5[1])*w5) + (bf2f(r6[1])*w6 + bf2f(r7[1])*w7));
                a2 += ((bf2f(r0[2])*w0 + bf2f(r1[2])*w1) + (bf2f(r2[2])*w2 + bf2f(r3[2])*w3))
                    + ((bf2f(r4[2])*w4 + bf2f(r5[2])*w5) + (bf2f(r6[2])*w6 + bf2f(r7[2])*w7));
                a3 += ((bf2f(r0[3])*w0 + bf2f(r1[3])*w1) + (bf2f(r2[3])*w2 + bf2f(r3[3])*w3))
                    + ((bf2f(r4[3])*w4 + bf2f(r5[3])*w5) + (bf2f(r6[3])*w6 + bf2f(r7[3])*w7));
            }
            for (; k + 1 < deg; k += 2) {
                int s0 = srcS[base + k], s1 = srcS[base + k + 1];
                float w0 = wS[base + k], w1 = wS[base + k + 1];
                us4 r0 = *(const us4*)&featb[(size_t)s0 * DIM + ql * 4];
                us4 r1 = *(const us4*)&featb[(size_t)s1 * DIM + ql * 4];
                a0 += bf2f(r0[0]) * w0 + bf2f(r1[0]) * w1;
                a1 += bf2f(r0[1]) * w0 + bf2f(r1[1]) * w1;
                a2 += bf2f(r0[2]) * w0 + bf2f(r1[2]) * w1;
                a3 += bf2f(r0[3]) * w0 + bf2f(r1[3]) * w1;
            }
            if (k < deg) {
                int s = srcS[base + k];
                float w = wS[base + k];
                us4 r = *(const us4*)&featb[(size_t)s * DIM + ql * 4];
                a0 += bf2f(r[0]) * w; a1 += bf2f(r[1]) * w;
                a2 += bf2f(r[2]) * w; a3 += bf2f(r[3]) * w;
            }
        }
        if (act) {
            float sc = rel ? 1.0f : 1.0f / fmaxf((float)deg, 1.0f);   // geo -> mean
            us4 o;
            o[0] = f2bf(a0 * sc); o[1] = f2bf(a1 * sc);
            o[2] = f2bf(a2 * sc); o[3] = f2bf(a3 * sc);
            size_t row = (size_t)(rel ? N_NODES + node0 + nl : node0 + nl);
            *(us4*)&zb[row * DIM + ql * 4] = o;
        }
    }
}

// ---------- Semantic-attention MLP via bf16 MFMA; A-frags loaded directly from zb ----
__global__ void __launch_bounds__(256) mlp_mfma_kernel(
        const unsigned short* __restrict__ zb,
        const unsigned short* __restrict__ W1p,
        const float* __restrict__ bias1, const float* __restrict__ W2,
        float* __restrict__ partials) {
    __shared__ float wred[4][2];
    int t = threadIdx.x, lane = t & 63, wave = t >> 6;
    int m = lane & 15, q = lane >> 4;
    int base = blockIdx.x * 64 + wave * 16;
    int R = base + m;

    const unsigned short* rowp = zb + (size_t)R * DIM;
    short8 a0 = *(const short8*)(rowp + q * 8);          // k = q*8..q*8+7
    short8 a1 = *(const short8*)(rowp + 32 + q * 8);     // k = 32+q*8..

    float c0 = 0.0f, c1 = 0.0f;
    const short8* W1v = (const short8*)W1p;   // 512 frags of 8 bf16

    #pragma unroll 4
    for (int n = 0; n < 16; ++n) {
        short8 b0 = W1v[(n * 2 + 0) * 64 + lane];
        short8 bK = W1v[(n * 2 + 1) * 64 + lane];
        f32x4 acc = {0.0f, 0.0f, 0.0f, 0.0f};
        acc = __builtin_amdgcn_mfma_f32_16x16x32_bf16(a0, b0, acc, 0, 0, 0);
        acc = __builtin_amdgcn_mfma_f32_16x16x32_bf16(a1, bK, acc, 0, 0, 0);
        int col = 16 * n + m;                 // C/D: col=lane&15, row=q*4+reg
        float bj = bias1[col];
        float w2 = W2[col];
        #pragma unroll
        for (int reg = 0; reg < 4; ++reg) {
            int Rr = base + q * 4 + reg;
            float h = tanh_fast(acc[reg] + bj);
            float contrib = h * w2;
            if (Rr < N_NODES) c0 += contrib; else c1 += contrib;
        }
    }

    #pragma unroll
    for (int off = 32; off > 0; off >>= 1) {
        c0 += __shfl_down(c0, off);
        c1 += __shfl_down(c1, off);
    }
    if (lane == 0) { wred[wave][0] = c0; wred[wave][1] = c1; }
    __syncthreads();
    if (t == 0) {
        partials[blockIdx.x * 2 + 0] = wred[0][0] + wred[1][0] + wred[2][0] + wred[3][0];
        partials[blockIdx.x * 2 + 1] = wred[0][1] + wred[1][1] + wred[2][1] + wred[3][1];
    }
}

__global__ void beta_kernel(const float* __restrict__ partials, float* __restrict__ beta) {
    __shared__ float wred[4][2];
    int t = threadIdx.x;
    float c0 = 0.0f, c1 = 0.0f;
    for (int i = t; i < MLP_ROWBLOCKS; i += 256) {
        c0 += partials[i * 2 + 0];
        c1 += partials[i * 2 + 1];
    }
    #pragma unroll
    for (int off = 32; off > 0; off >>= 1) {
        c0 += __shfl_down(c0, off);
        c1 += __shfl_down(c1, off);
    }
    int lane = t & 63, wv = t >> 6;
    if (lane == 0) { wred[wv][0] = c0; wred[wv][1] = c1; }
    __syncthreads();
    if (t == 0) {
        float s0 = (wred[0][0] + wred[1][0] + wred[2][0] + wred[3][0]) / (float)N_NODES;
        float s1 = (wred[0][1] + wred[1][1] + wred[2][1] + wred[3][1]) / (float)N_NODES;
        float m = fmaxf(s0, s1);
        float e0 = __expf(s0 - m), e1 = __expf(s1 - m);
        float inv = 1.0f / (e0 + e1);
        beta[0] = e0 * inv;
        beta[1] = e1 * inv;
    }
}

// out = beta0 * geo_mean + beta1 * trans, reading bf16 z.
__global__ void combine_kernel(const unsigned short* __restrict__ zb,
                               const float* __restrict__ beta,
                               float* __restrict__ out) {
    int gid = blockIdx.x * 256 + threadIdx.x;   // 8 elements per thread
    float b0 = beta[0];
    float b1 = beta[1];
    uint4 g = *(const uint4*)&zb[(size_t)gid * 8];
    uint4 tr = *(const uint4*)&zb[(size_t)N_NODES * DIM + (size_t)gid * 8];
    float4 o0, o1;
    o0.x = b0 * __uint_as_float(g.x << 16) + b1 * __uint_as_float(tr.x << 16);
    o0.y = b0 * __uint_as_float(g.x & 0xFFFF0000u) + b1 * __uint_as_float(tr.x & 0xFFFF0000u);
    o0.z = b0 * __uint_as_float(g.y << 16) + b1 * __uint_as_float(tr.y << 16);
    o0.w = b0 * __uint_as_float(g.y & 0xFFFF0000u) + b1 * __uint_as_float(tr.y & 0xFFFF0000u);
    o1.x = b0 * __uint_as_float(g.z << 16) + b1 * __uint_as_float(tr.z << 16);
    o1.y = b0 * __uint_as_float(g.z & 0xFFFF0000u) + b1 * __uint_as_float(tr.z & 0xFFFF0000u);
    o1.z = b0 * __uint_as_float(g.w << 16) + b1 * __uint_as_float(tr.w << 16);
    o1.w = b0 * __uint_as_float(g.w & 0xFFFF0000u) + b1 * __uint_as_float(tr.w & 0xFFFF0000u);
    *(float4*)&out[(size_t)gid * 8] = o0;
    *(float4*)&out[(size_t)gid * 8 + 4] = o1;
}

extern "C" void kernel_launch(void* const* d_in, const int* in_sizes, int n_in,
                              void* d_out, int out_size, void* d_ws, size_t ws_size,
                              hipStream_t stream) {
    const float* loc_feat = (const float*)d_in[0];
    const int* geo_src    = (const int*)d_in[1];
    const int* geo_dst    = (const int*)d_in[2];
    const int* trans_src  = (const int*)d_in[3];
    const int* trans_dst  = (const int*)d_in[4];
    const float* trans_w  = (const float*)d_in[5];
    const float* W1       = (const float*)d_in[6];
    const float* b1       = (const float*)d_in[7];
    const float* W2       = (const float*)d_in[8];
    float* out = (float*)d_out;

    // ws layout (4B units): [gcount 2*NBINS][gbin NBINS*CAP int][tbin NBINS*CAP int2]
    //   [partials 2*3125][beta 2][W1p 16384 u16][featb N*64 u16][zb 2N*64 u16]  ~55 MB
    int*   gcount   = (int*)d_ws;
    int*   gbin     = gcount + 2 * NBINS;
    int2*  tbin     = (int2*)(gbin + (size_t)NBINS * CAP);
    float* partials = (float*)(tbin + (size_t)NBINS * CAP);
    float* beta     = partials + 2 * MLP_ROWBLOCKS;
    unsigned short* W1p   = (unsigned short*)(beta + 2);
    unsigned short* featb = W1p + 16384;
    unsigned short* zb    = featb + (size_t)N_NODES * DIM;

    hipMemsetAsync(gcount, 0, 2 * NBINS * sizeof(int), stream);

    pack_kernel<<<FEAT_BLOCKS + 1, 256, 0, stream>>>(loc_feat, featb, W1, W1p);
    bin_fill_kernel<<<2 * FILL_BLOCKS, 512, 0, stream>>>(geo_src, geo_dst, trans_src,
                                                         trans_dst, trans_w,
                                                         gcount, gbin, tbin);
    aggregate_kernel<<<2 * NBINS, 256, 0, stream>>>(featb, gbin, tbin, gcount, zb);
    mlp_mfma_kernel<<<MLP_ROWBLOCKS, 256, 0, stream>>>(zb, W1p, b1, W2, partials);
    beta_kernel<<<1, 256, 0, stream>>>(partials, beta);
    combine_kernel<<<(N_NODES * DIM / 8) / 256, 256, 0, stream>>>(zb, beta, out);
}